// Round 2
// baseline (369.730 us; speedup 1.0000x reference)
//
#include <hip/hip_runtime.h>

#define BATCH 16
#define HW (768 * 768)     // 589824 pixels per batch-image
#define NIDS 128
#define GROUPS (HW / 4)    // 147456 int4/float4 groups per batch
#define NBLK 144           // blocks per batch: 144*256 threads -> exactly 4 groups/thread

// ---------------------------------------------------------------------------
// ws layout (zeroed by one 24 KB memset each call):
//   [0,     8192) : float    g_sin[16][128]   per-(b,id) sum of |psin-gsin|
//   [8192, 16384) : float    g_cos[16][128]   per-(b,id) sum of |pcos-gcos|
//   [16384,24576) : unsigned g_cnt[16][128]   per-(b,id) pixel count
// ---------------------------------------------------------------------------

__global__ __launch_bounds__(256) void fused_kernel(const int* __restrict__ inst,
                                                    const float* __restrict__ pred,
                                                    const float* __restrict__ gt,
                                                    float* __restrict__ g_sin,
                                                    float* __restrict__ g_cos,
                                                    unsigned int* __restrict__ g_cnt) {
    // wave-private accumulators: 4 waves x 128 ids x (sin,cos,cnt)
    __shared__ float        s_sin[4][NIDS];
    __shared__ float        s_cos[4][NIDS];
    __shared__ unsigned int s_cnt[4][NIDS];

    const int b = blockIdx.y;
    for (int i = threadIdx.x; i < 4 * NIDS; i += 256) {
        s_sin[i >> 7][i & 127] = 0.0f;
        s_cos[i >> 7][i & 127] = 0.0f;
        s_cnt[i >> 7][i & 127] = 0u;
    }
    __syncthreads();

    const int wid = threadIdx.x >> 6;
    const int4*   ip = (const int4*)  (inst + (size_t)b * HW);
    const float4* ps = (const float4*)(pred + (size_t)b * 2 * HW);
    const float4* pc = (const float4*)(pred + (size_t)b * 2 * HW + HW);
    const float4* gs = (const float4*)(gt   + (size_t)b * 5 * HW + 2 * (size_t)HW);
    const float4* gc = (const float4*)(gt   + (size_t)b * 5 * HW + 3 * (size_t)HW);

    for (int g = blockIdx.x * 256 + threadIdx.x; g < GROUPS; g += NBLK * 256) {
        const int4   v = ip[g];
        const float4 a = ps[g];
        const float4 p = pc[g];
        const float4 c = gs[g];
        const float4 d = gc[g];

        const int i0 = v.x & 127, i1 = v.y & 127, i2 = v.z & 127, i3 = v.w & 127;
        atomicAdd(&s_sin[wid][i0], fabsf(a.x - c.x));
        atomicAdd(&s_cos[wid][i0], fabsf(p.x - d.x));
        atomicAdd(&s_cnt[wid][i0], 1u);
        atomicAdd(&s_sin[wid][i1], fabsf(a.y - c.y));
        atomicAdd(&s_cos[wid][i1], fabsf(p.y - d.y));
        atomicAdd(&s_cnt[wid][i1], 1u);
        atomicAdd(&s_sin[wid][i2], fabsf(a.z - c.z));
        atomicAdd(&s_cos[wid][i2], fabsf(p.z - d.z));
        atomicAdd(&s_cnt[wid][i2], 1u);
        atomicAdd(&s_sin[wid][i3], fabsf(a.w - c.w));
        atomicAdd(&s_cos[wid][i3], fabsf(p.w - d.w));
        atomicAdd(&s_cnt[wid][i3], 1u);
    }
    __syncthreads();

    // combine the 4 wave-private arrays, one thread per id, then one global
    // atomic per (id, quantity): 128 threads x 3 atomics per block
    if (threadIdx.x < NIDS) {
        const int id = threadIdx.x;
        const float fs = s_sin[0][id] + s_sin[1][id] + s_sin[2][id] + s_sin[3][id];
        const float fc = s_cos[0][id] + s_cos[1][id] + s_cos[2][id] + s_cos[3][id];
        const unsigned int n = s_cnt[0][id] + s_cnt[1][id] + s_cnt[2][id] + s_cnt[3][id];
        if (n) {  // skip empty bins: fewer global atomics
            atomicAdd(&g_sin[b * NIDS + id], fs);
            atomicAdd(&g_cos[b * NIDS + id], fc);
            atomicAdd(&g_cnt[b * NIDS + id], n);
        }
    }
}

__global__ __launch_bounds__(256) void fin_kernel(const float* __restrict__ g_sin,
                                                  const float* __restrict__ g_cos,
                                                  const unsigned int* __restrict__ g_cnt,
                                                  float* __restrict__ out) {
    // single block, 256 threads
    __shared__ float s_ls[BATCH], s_lc[BATCH];
    __shared__ unsigned int s_ni[4], s_nb[4];
    __shared__ float s_f[2];

    if (threadIdx.x < BATCH) { s_ls[threadIdx.x] = 0.0f; s_lc[threadIdx.x] = 0.0f; }

    // global scalars: num_instances (fg bins with count>0, all batches), num_bg
    unsigned int ninst = 0u, nbg = 0u;
    for (int i = threadIdx.x; i < BATCH * NIDS; i += 256) {
        const unsigned int c = g_cnt[i];
        if ((i & 127) == 0) nbg += c;
        else ninst += (c > 0u) ? 1u : 0u;
    }
    for (int off = 32; off; off >>= 1) {
        ninst += __shfl_down(ninst, off, 64);
        nbg   += __shfl_down(nbg,   off, 64);
    }
    const int wid = threadIdx.x >> 6, lane = threadIdx.x & 63;
    if (lane == 0) { s_ni[wid] = ninst; s_nb[wid] = nbg; }
    __syncthreads();
    if (threadIdx.x == 0) {
        unsigned int a = 0u, c = 0u;
        for (int i = 0; i < 4; ++i) { a += s_ni[i]; c += s_nb[i]; }
        s_f[0] = (float)a;
        s_f[1] = (float)c;
    }
    __syncthreads();
    const float num_instances = s_f[0];
    const float num_bg = s_f[1];

    // weighted combine: loss_sin[b] = sum_id g_sin[b][id] / norm(b,id)
    for (int i = threadIdx.x; i < BATCH * NIDS; i += 256) {
        const int bb = i >> 7, id = i & 127;
        const float c = (float)g_cnt[i];
        const float norm = (id == 0) ? (num_bg * 2.0f)
                                     : (fmaxf(c, 1.0f) * num_instances * 2.0f);
        const float w = 1.0f / norm;
        atomicAdd(&s_ls[bb], g_sin[i] * w);
        atomicAdd(&s_lc[bb], g_cos[i] * w);
    }
    __syncthreads();

    if (threadIdx.x < BATCH) {
        const int b = threadIdx.x;
        const float s = s_ls[b];
        const float c = s_lc[b];
        const float tot = s + c;
        out[b]      = tot;   // loss
        out[16 + b] = tot;   // loss_direction_total
        out[32 + b] = 0.0f;  // loss_centers
        out[48 + b] = s;     // loss_sin
        out[64 + b] = c;     // loss_cos
    }
}

extern "C" void kernel_launch(void* const* d_in, const int* in_sizes, int n_in,
                              void* d_out, int out_size, void* d_ws, size_t ws_size,
                              hipStream_t stream) {
    const float* prediction = (const float*)d_in[0];
    const int*   instances  = (const int*)d_in[1];
    // d_in[2] = labels: unused (W_BG == W_FG == 1.0 makes the base weight 1.0)
    const float* centerdir  = (const float*)d_in[3];
    float* out = (float*)d_out;

    float*        g_sin = (float*)d_ws;
    float*        g_cos = (float*)((char*)d_ws + 8192);
    unsigned int* g_cnt = (unsigned int*)((char*)d_ws + 16384);

    hipMemsetAsync(d_ws, 0, 24576, stream);

    fused_kernel<<<dim3(NBLK, BATCH), 256, 0, stream>>>(instances, prediction, centerdir,
                                                        g_sin, g_cos, g_cnt);
    fin_kernel<<<1, 256, 0, stream>>>(g_sin, g_cos, g_cnt, out);
}

// Round 3
// 359.665 us; speedup vs baseline: 1.0280x; 1.0280x over previous
//
#include <hip/hip_runtime.h>

#define BATCH 16
#define HW (768 * 768)       // 589824 pixels per batch-image
#define NIDS 128
#define GROUPS (HW / 4)      // 147456 int4/float4 groups per batch
#define NBLK 96              // blocks per batch -> 1536 blocks = 6/CU (LDS-limited)
#define ITERS 6              // GROUPS / (NBLK*256) exactly
#define NCOPY 16             // replicated LDS accumulator copies per block (4/wave)
#define CSTR 129             // copy stride in words: copy c starts at bank c

// ---------------------------------------------------------------------------
// ws layout (zeroed by one 24 KB memset each call):
//   [0,     8192) : float    g_sin[16][128]   per-(b,id) sum of |psin-gsin|
//   [8192, 16384) : float    g_cos[16][128]   per-(b,id) sum of |pcos-gcos|
//   [16384,24576) : unsigned g_cnt[16][128]   per-(b,id) pixel count
// ---------------------------------------------------------------------------

__global__ __launch_bounds__(256) void fused_kernel(const int* __restrict__ inst,
                                                    const float* __restrict__ pred,
                                                    const float* __restrict__ gt,
                                                    float* __restrict__ g_sin,
                                                    float* __restrict__ g_cos,
                                                    unsigned int* __restrict__ g_cnt) {
    // 16 replicated accumulator copies (4 per wave, lane l uses copy l&3):
    // same-address atomic collisions only among the 16 lanes sharing a copy.
    __shared__ float        s_sin[NCOPY * CSTR];
    __shared__ float        s_cos[NCOPY * CSTR];
    __shared__ unsigned int s_cnt[NCOPY * CSTR];

    const int b = blockIdx.y;
    for (int i = threadIdx.x; i < NCOPY * CSTR; i += 256) {
        s_sin[i] = 0.0f; s_cos[i] = 0.0f; s_cnt[i] = 0u;
    }
    __syncthreads();

    const int copy = ((threadIdx.x >> 6) << 2) + (threadIdx.x & 3);
    const int base = copy * CSTR;

    const int4*   ip = (const int4*)  (inst + (size_t)b * HW);
    const float4* ps = (const float4*)(pred + (size_t)b * 2 * HW);
    const float4* pc = (const float4*)(pred + (size_t)b * 2 * HW + HW);
    const float4* gs = (const float4*)(gt   + (size_t)b * 5 * HW + 2 * (size_t)HW);
    const float4* gc = (const float4*)(gt   + (size_t)b * 5 * HW + 3 * (size_t)HW);

    int g = blockIdx.x * 256 + threadIdx.x;
    #pragma unroll
    for (int it = 0; it < ITERS; ++it, g += NBLK * 256) {
        const int4   v = ip[g];
        const float4 a = ps[g];
        const float4 p = pc[g];
        const float4 c = gs[g];
        const float4 d = gc[g];

        const int i0 = base + (v.x & 127), i1 = base + (v.y & 127);
        const int i2 = base + (v.z & 127), i3 = base + (v.w & 127);
        atomicAdd(&s_sin[i0], fabsf(a.x - c.x));
        atomicAdd(&s_cos[i0], fabsf(p.x - d.x));
        atomicAdd(&s_cnt[i0], 1u);
        atomicAdd(&s_sin[i1], fabsf(a.y - c.y));
        atomicAdd(&s_cos[i1], fabsf(p.y - d.y));
        atomicAdd(&s_cnt[i1], 1u);
        atomicAdd(&s_sin[i2], fabsf(a.z - c.z));
        atomicAdd(&s_cos[i2], fabsf(p.z - d.z));
        atomicAdd(&s_cnt[i2], 1u);
        atomicAdd(&s_sin[i3], fabsf(a.w - c.w));
        atomicAdd(&s_cos[i3], fabsf(p.w - d.w));
        atomicAdd(&s_cnt[i3], 1u);
    }
    __syncthreads();

    // combine the 16 copies; one global atomic per (id, quantity)
    if (threadIdx.x < NIDS) {
        const int id = threadIdx.x;
        float fs = 0.0f, fc = 0.0f;
        unsigned int n = 0u;
        #pragma unroll
        for (int cny = 0; cny < NCOPY; ++cny) {
            fs += s_sin[cny * CSTR + id];
            fc += s_cos[cny * CSTR + id];
            n  += s_cnt[cny * CSTR + id];
        }
        if (n) {
            atomicAdd(&g_sin[b * NIDS + id], fs);
            atomicAdd(&g_cos[b * NIDS + id], fc);
            atomicAdd(&g_cnt[b * NIDS + id], n);
        }
    }
}

__global__ __launch_bounds__(256) void fin_kernel(const float* __restrict__ g_sin,
                                                  const float* __restrict__ g_cos,
                                                  const unsigned int* __restrict__ g_cnt,
                                                  float* __restrict__ out) {
    // single block, 256 threads
    __shared__ float s_ls[BATCH], s_lc[BATCH];
    __shared__ unsigned int s_ni[4], s_nb[4];
    __shared__ float s_f[2];

    if (threadIdx.x < BATCH) { s_ls[threadIdx.x] = 0.0f; s_lc[threadIdx.x] = 0.0f; }

    unsigned int ninst = 0u, nbg = 0u;
    for (int i = threadIdx.x; i < BATCH * NIDS; i += 256) {
        const unsigned int c = g_cnt[i];
        if ((i & 127) == 0) nbg += c;
        else ninst += (c > 0u) ? 1u : 0u;
    }
    for (int off = 32; off; off >>= 1) {
        ninst += __shfl_down(ninst, off, 64);
        nbg   += __shfl_down(nbg,   off, 64);
    }
    const int wid = threadIdx.x >> 6, lane = threadIdx.x & 63;
    if (lane == 0) { s_ni[wid] = ninst; s_nb[wid] = nbg; }
    __syncthreads();
    if (threadIdx.x == 0) {
        unsigned int a = 0u, c = 0u;
        for (int i = 0; i < 4; ++i) { a += s_ni[i]; c += s_nb[i]; }
        s_f[0] = (float)a;
        s_f[1] = (float)c;
    }
    __syncthreads();
    const float num_instances = s_f[0];
    const float num_bg = s_f[1];

    for (int i = threadIdx.x; i < BATCH * NIDS; i += 256) {
        const int bb = i >> 7, id = i & 127;
        const float c = (float)g_cnt[i];
        const float norm = (id == 0) ? (num_bg * 2.0f)
                                     : (fmaxf(c, 1.0f) * num_instances * 2.0f);
        const float w = 1.0f / norm;
        atomicAdd(&s_ls[bb], g_sin[i] * w);
        atomicAdd(&s_lc[bb], g_cos[i] * w);
    }
    __syncthreads();

    if (threadIdx.x < BATCH) {
        const int b = threadIdx.x;
        const float s = s_ls[b];
        const float c = s_lc[b];
        const float tot = s + c;
        out[b]      = tot;   // loss
        out[16 + b] = tot;   // loss_direction_total
        out[32 + b] = 0.0f;  // loss_centers
        out[48 + b] = s;     // loss_sin
        out[64 + b] = c;     // loss_cos
    }
}

extern "C" void kernel_launch(void* const* d_in, const int* in_sizes, int n_in,
                              void* d_out, int out_size, void* d_ws, size_t ws_size,
                              hipStream_t stream) {
    const float* prediction = (const float*)d_in[0];
    const int*   instances  = (const int*)d_in[1];
    // d_in[2] = labels: unused (W_BG == W_FG == 1.0 makes the base weight 1.0)
    const float* centerdir  = (const float*)d_in[3];
    float* out = (float*)d_out;

    float*        g_sin = (float*)d_ws;
    float*        g_cos = (float*)((char*)d_ws + 8192);
    unsigned int* g_cnt = (unsigned int*)((char*)d_ws + 16384);

    hipMemsetAsync(d_ws, 0, 24576, stream);

    fused_kernel<<<dim3(NBLK, BATCH), 256, 0, stream>>>(instances, prediction, centerdir,
                                                        g_sin, g_cos, g_cnt);
    fin_kernel<<<1, 256, 0, stream>>>(g_sin, g_cos, g_cnt, out);
}

// Round 7
// 333.171 us; speedup vs baseline: 1.1097x; 1.0795x over previous
//
#include <hip/hip_runtime.h>

#define BATCH 16
#define HW (768 * 768)       // 589824 pixels per batch-image
#define NIDS 128
#define GROUPS (HW / 4)      // 147456 int4/float4 groups per batch
#define HBLK 72              // hist blocks per batch: 72*256 thr * 8 iters * 4 px = HW
#define LBLK 144             // loss blocks per batch: 144*256 thr * 4 iters * 4 px = HW

typedef float f4 __attribute__((ext_vector_type(4)));

// ---------------------------------------------------------------------------
// ws layout (one 16.5 KB memset per call):
//   [0,     8192) : unsigned counts[16][128]
//   [8192, 16384) : float    inv_norm[16][128]
//   [16384,16512) : float    sums[32]   (sums[b]=sin, sums[16+b]=cos)
// ---------------------------------------------------------------------------

// Per-thread private u8 histograms: no atomics at all in the hot loop.
// Increment = ds_read_u8 + ds_write_b8 (~6cyc each) vs ~130cyc wave64 LDS atomic.
__global__ __launch_bounds__(256) void hist_kernel(const int* __restrict__ inst,
                                                   unsigned int* __restrict__ counts) {
    __shared__ unsigned int cnt32[256 * 32];   // u8[256][128], u32-aligned view
    __shared__ unsigned int tmp[8 * 128];      // merge scratch: [slice][id]
    unsigned char* cnt = (unsigned char*)cnt32;

    const int b = blockIdx.y;
    for (int i = threadIdx.x; i < 256 * 32; i += 256) cnt32[i] = 0u;
    __syncthreads();

    const int4* src = (const int4*)(inst + (size_t)b * HW);
    unsigned char* my = cnt + threadIdx.x * 128;   // this thread's private bins

    int g = blockIdx.x * 256 + threadIdx.x;
    #pragma unroll
    for (int it = 0; it < 8; ++it, g += HBLK * 256) {
        const int4 v = src[g];
        ++my[v.x & 127];
        ++my[v.y & 127];
        ++my[v.z & 127];
        ++my[v.w & 127];
    }
    __syncthreads();

    // merge 256 private u8 arrays -> 128 block totals.
    // thread = (idg = tid&31: 4 ids via one u32; h = tid>>5: 32-row slice)
    // u32 read bank = idg -> 2 lanes/bank across a wave64 = conflict-free.
    const int idg = threadIdx.x & 31, h = threadIdx.x >> 5;
    unsigned s0 = 0, s1 = 0, s2 = 0, s3 = 0;
    #pragma unroll
    for (int r = 0; r < 32; ++r) {
        const unsigned v = cnt32[(h * 32 + r) * 32 + idg];
        s0 += v & 255u; s1 += (v >> 8) & 255u; s2 += (v >> 16) & 255u; s3 += v >> 24;
    }
    tmp[h * 128 + idg * 4 + 0] = s0;
    tmp[h * 128 + idg * 4 + 1] = s1;
    tmp[h * 128 + idg * 4 + 2] = s2;
    tmp[h * 128 + idg * 4 + 3] = s3;
    __syncthreads();

    if (threadIdx.x < NIDS) {
        unsigned t = 0;
        #pragma unroll
        for (int hh = 0; hh < 8; ++hh) t += tmp[hh * 128 + threadIdx.x];
        if (t) atomicAdd(&counts[b * NIDS + threadIdx.x], t);
    }
}

__global__ __launch_bounds__(256) void norm_kernel(const unsigned int* __restrict__ counts,
                                                   float* __restrict__ inv_norm) {
    // single block of 256 threads
    unsigned int ninst = 0u, nbg = 0u;
    for (int i = threadIdx.x; i < BATCH * NIDS; i += 256) {
        const unsigned int c = counts[i];
        if ((i & 127) == 0) nbg += c;
        else ninst += (c > 0u) ? 1u : 0u;
    }
    for (int off = 32; off; off >>= 1) {
        ninst += __shfl_down(ninst, off, 64);
        nbg   += __shfl_down(nbg,   off, 64);
    }
    __shared__ unsigned int s_ni[4], s_nb[4];
    __shared__ float s_f[2];
    const int wid = threadIdx.x >> 6, lane = threadIdx.x & 63;
    if (lane == 0) { s_ni[wid] = ninst; s_nb[wid] = nbg; }
    __syncthreads();
    if (threadIdx.x == 0) {
        unsigned int a = 0u, c = 0u;
        for (int i = 0; i < 4; ++i) { a += s_ni[i]; c += s_nb[i]; }
        s_f[0] = (float)a;   // num_instances
        s_f[1] = (float)c;   // num_bg_pixels
    }
    __syncthreads();
    const float num_instances = s_f[0];
    const float num_bg = s_f[1];
    for (int i = threadIdx.x; i < BATCH * NIDS; i += 256) {
        const float c = (float)counts[i];
        const float norm = ((i & 127) == 0) ? (num_bg * 2.0f)
                                            : (fmaxf(c, 1.0f) * num_instances * 2.0f);
        inv_norm[i] = 1.0f / norm;
    }
}

__global__ __launch_bounds__(256) void loss_kernel(const int* __restrict__ inst,
                                                   const float* __restrict__ pred,
                                                   const float* __restrict__ gt,
                                                   const float* __restrict__ inv_norm,
                                                   float* __restrict__ sums) {
    __shared__ float tbl[NIDS];
    const int b = blockIdx.y;
    for (int i = threadIdx.x; i < NIDS; i += 256) tbl[i] = inv_norm[b * NIDS + i];
    __syncthreads();

    const int4* ip = (const int4*)(inst + (size_t)b * HW);
    const f4*   ps = (const f4*)  (pred + (size_t)b * 2 * HW);
    const f4*   pc = (const f4*)  (pred + (size_t)b * 2 * HW + HW);
    const f4*   gs = (const f4*)  (gt   + (size_t)b * 5 * HW + 2 * (size_t)HW);
    const f4*   gc = (const f4*)  (gt   + (size_t)b * 5 * HW + 3 * (size_t)HW);

    float acc_s = 0.0f, acc_c = 0.0f;
    int g = blockIdx.x * 256 + threadIdx.x;
    #pragma unroll
    for (int it = 0; it < 4; ++it, g += LBLK * 256) {
        const int4 v = ip[g];                              // keep cached (read twice)
        const f4 a = __builtin_nontemporal_load(ps + g);   // streamed once: nt
        const f4 p = __builtin_nontemporal_load(pc + g);
        const f4 c = __builtin_nontemporal_load(gs + g);
        const f4 d = __builtin_nontemporal_load(gc + g);
        const float w0 = tbl[v.x & 127];
        const float w1 = tbl[v.y & 127];
        const float w2 = tbl[v.z & 127];
        const float w3 = tbl[v.w & 127];
        acc_s += w0 * fabsf(a.x - c.x) + w1 * fabsf(a.y - c.y) +
                 w2 * fabsf(a.z - c.z) + w3 * fabsf(a.w - c.w);
        acc_c += w0 * fabsf(p.x - d.x) + w1 * fabsf(p.y - d.y) +
                 w2 * fabsf(p.z - d.z) + w3 * fabsf(p.w - d.w);
    }

    for (int off = 32; off; off >>= 1) {
        acc_s += __shfl_down(acc_s, off, 64);
        acc_c += __shfl_down(acc_c, off, 64);
    }
    __shared__ float s_s[4], s_c[4];
    const int wid = threadIdx.x >> 6, lane = threadIdx.x & 63;
    if (lane == 0) { s_s[wid] = acc_s; s_c[wid] = acc_c; }
    __syncthreads();
    if (threadIdx.x == 0) {
        float ts = 0.0f, tc = 0.0f;
        for (int i = 0; i < 4; ++i) { ts += s_s[i]; tc += s_c[i]; }
        atomicAdd(&sums[b], ts);
        atomicAdd(&sums[BATCH + b], tc);
    }
}

__global__ void fin_kernel(const float* __restrict__ sums, float* __restrict__ out) {
    const int b = threadIdx.x;
    if (b < BATCH) {
        const float s = sums[b];
        const float c = sums[BATCH + b];
        const float tot = s + c;
        out[b]      = tot;   // loss
        out[16 + b] = tot;   // loss_direction_total
        out[32 + b] = 0.0f;  // loss_centers
        out[48 + b] = s;     // loss_sin
        out[64 + b] = c;     // loss_cos
    }
}

extern "C" void kernel_launch(void* const* d_in, const int* in_sizes, int n_in,
                              void* d_out, int out_size, void* d_ws, size_t ws_size,
                              hipStream_t stream) {
    const float* prediction = (const float*)d_in[0];
    const int*   instances  = (const int*)d_in[1];
    // d_in[2] = labels: unused (W_BG == W_FG == 1.0 makes the base weight 1.0)
    const float* centerdir  = (const float*)d_in[3];
    float* out = (float*)d_out;

    unsigned int* counts   = (unsigned int*)d_ws;
    float*        inv_norm = (float*)((char*)d_ws + 8192);
    float*        sums     = (float*)((char*)d_ws + 16384);

    hipMemsetAsync(d_ws, 0, 16512, stream);   // counts + inv_norm + sums

    hist_kernel<<<dim3(HBLK, BATCH), 256, 0, stream>>>(instances, counts);
    norm_kernel<<<1, 256, 0, stream>>>(counts, inv_norm);
    loss_kernel<<<dim3(LBLK, BATCH), 256, 0, stream>>>(instances, prediction, centerdir,
                                                       inv_norm, sums);
    fin_kernel<<<1, 64, 0, stream>>>(sums, out);
}